// Round 9
// baseline (228.106 us; speedup 1.0000x reference)
//
#include <hip/hip_runtime.h>
#include <stdint.h>

#define SEQ 4096
#define EMB 768
#define HEADS 12
#define HD 64

typedef __attribute__((ext_vector_type(8))) short short8;
typedef __attribute__((ext_vector_type(4))) short short4v;
typedef __attribute__((ext_vector_type(8))) __bf16 bf16x8;
typedef __attribute__((ext_vector_type(4))) __bf16 bf16x4;
typedef __attribute__((ext_vector_type(4))) float f32x4;

// scale * log2(e) folded into Q: (1/sqrt(64)) * 1.4426950408889634
#define QSCALE 0.18033688011112043f

// chunks per 128-q tile i (k-tiles T = 2i+2, chunk <= 14 tiles)
#define NCH(i) ((2 * (i) + 15) / 14)

static __device__ __forceinline__ unsigned short f2bf(float f) {
    unsigned int u = __builtin_bit_cast(unsigned int, f);
    unsigned int r = 0x7fffu + ((u >> 16) & 1u);
    u += r;
    return (unsigned short)(u >> 16);
}

static __device__ __forceinline__ f32x4 mfma32(short8 a, short8 b, f32x4 c) {
    return __builtin_amdgcn_mfma_f32_16x16x32_bf16(
        __builtin_bit_cast(bf16x8, a), __builtin_bit_cast(bf16x8, b), c, 0, 0, 0);
}

static __device__ __forceinline__ f32x4 mfma16(short4v a, short4v b, f32x4 c) {
#if __has_builtin(__builtin_amdgcn_mfma_f32_16x16x16_bf16)
    return __builtin_amdgcn_mfma_f32_16x16x16_bf16(
        __builtin_bit_cast(bf16x4, a), __builtin_bit_cast(bf16x4, b), c, 0, 0, 0);
#else
    return __builtin_amdgcn_mfma_f32_16x16x16bf16_1k(a, b, c, 0, 0, 0);
#endif
}

static __device__ __forceinline__ short4v pack4bf(float a, float b, float c, float d) {
#if __has_builtin(__builtin_amdgcn_cvt_pk_bf16_f32)
    typedef __attribute__((ext_vector_type(2))) __bf16 bf16x2;
    bf16x2 lo = __builtin_amdgcn_cvt_pk_bf16_f32(a, b);
    bf16x2 hi = __builtin_amdgcn_cvt_pk_bf16_f32(c, d);
    uint2 u = {__builtin_bit_cast(unsigned int, lo), __builtin_bit_cast(unsigned int, hi)};
    return __builtin_bit_cast(short4v, u);
#else
    short4v p;
    p[0] = (short)f2bf(a); p[1] = (short)f2bf(b);
    p[2] = (short)f2bf(c); p[3] = (short)f2bf(d);
    return p;
#endif
}

static __device__ __forceinline__ void load_lds16(const void* g, void* l) {
    __builtin_amdgcn_global_load_lds(
        (const __attribute__((address_space(1))) unsigned int*)(uintptr_t)g,
        (__attribute__((address_space(3))) unsigned int*)(uintptr_t)l, 16, 0, 0);
}

// dense partial base for (h, i128): 58 partial slots per head
static __device__ __forceinline__ int pid_base(int h, int i128) {
    int pb = 0;
    for (int j = i128 + 1; j < 32; ++j) pb += NCH(j) - 1;
    return h * 58 + pb;
}

// online-softmax step over one 64-k tile held as st[4] (S^T layout)
static __device__ __forceinline__ void softmax_step(f32x4* st, float& m_i, float& l_i,
                                                    f32x4* O, short4v* pk) {
    float mx = -3.0e38f;
    for (int nt = 0; nt < 4; nt++)
        for (int r = 0; r < 4; r++) mx = fmaxf(mx, st[nt][r]);
    mx = fmaxf(mx, __shfl_xor(mx, 16));
    mx = fmaxf(mx, __shfl_xor(mx, 32));
    const bool inc = mx > m_i;
    if (__ballot(inc)) {
        const float mn = inc ? mx : m_i;
        const float alpha = __builtin_amdgcn_exp2f(m_i - mn);
        m_i = mn;
        l_i *= alpha;
        for (int dt = 0; dt < 4; dt++)
            for (int r = 0; r < 4; r++) O[dt][r] *= alpha;
    }
    float rs = 0.f;
    for (int nt = 0; nt < 4; nt++) {
        float p0 = __builtin_amdgcn_exp2f(st[nt][0] - m_i);
        float p1 = __builtin_amdgcn_exp2f(st[nt][1] - m_i);
        float p2 = __builtin_amdgcn_exp2f(st[nt][2] - m_i);
        float p3 = __builtin_amdgcn_exp2f(st[nt][3] - m_i);
        rs += p0 + p1 + p2 + p3;
        pk[nt] = pack4bf(p0, p1, p2, p3);
    }
    rs += __shfl_xor(rs, 16);
    rs += __shfl_xor(rs, 32);
    l_i += rs;
}

// ---------------------------------------------------------------- fused convert
__global__ __launch_bounds__(256) void convert_all(const float* __restrict__ x,
                                                   const float* __restrict__ wq,
                                                   const float* __restrict__ wk,
                                                   const float* __restrict__ wv,
                                                   const float* __restrict__ wo,
                                                   unsigned short* __restrict__ xb,
                                                   unsigned short* __restrict__ wqkvT,
                                                   unsigned short* __restrict__ woT) {
    __shared__ float Ls[64][65];
    const int bid = blockIdx.x;
    if (bid < 3072) {
        int i = bid * 256 + threadIdx.x;
        float4 v = ((const float4*)x)[i];
        ushort4 o = {f2bf(v.x), f2bf(v.y), f2bf(v.z), f2bf(v.w)};
        ((ushort4*)xb)[i] = o;
        return;
    }
    const int idx = bid - 3072;
    const int z = idx / 144;
    const int bx = (idx % 144) / 12, by = idx % 12;
    const float* W = (z == 0) ? wq : (z == 1) ? wk : (z == 2) ? wv : wo;
    unsigned short* dst = (z < 3) ? (wqkvT + (size_t)z * EMB * EMB) : woT;
    const int k0 = bx * 64, n0 = by * 64;
    const int r = threadIdx.x >> 2, c0 = (threadIdx.x & 3) * 16;
    for (int j = 0; j < 16; j += 4) {
        float4 v = *(const float4*)&W[(size_t)(k0 + r) * EMB + n0 + c0 + j];
        Ls[r][c0 + j] = v.x;
        Ls[r][c0 + j + 1] = v.y;
        Ls[r][c0 + j + 2] = v.z;
        Ls[r][c0 + j + 3] = v.w;
    }
    __syncthreads();
    unsigned short tmp[16];
    for (int j = 0; j < 16; j++) tmp[j] = f2bf(Ls[c0 + j][r]);
    *(uint4*)&dst[(size_t)(n0 + r) * EMB + k0 + c0] = *(uint4*)tmp;
    *(uint4*)&dst[(size_t)(n0 + r) * EMB + k0 + c0 + 8] = *(uint4*)(tmp + 8);
}

// ---------------------------------------------------------------- 128x128 QKV GEMM
__global__ __launch_bounds__(256) void gemm_qkv(const unsigned short* __restrict__ A,
                                                const unsigned short* __restrict__ Bt,
                                                const float* __restrict__ b0p,
                                                const float* __restrict__ b1p,
                                                const float* __restrict__ b2p,
                                                unsigned short* __restrict__ QKb,
                                                unsigned short* __restrict__ Vtb) {
    __shared__ __align__(16) unsigned short SMEM[16384];  // 32 KB
    unsigned short* As0 = SMEM;
    unsigned short* Bs0 = SMEM + 4096;
    unsigned short* As1 = SMEM + 8192;
    unsigned short* Bs1 = SMEM + 12288;
    const int tid = threadIdx.x;
    const int wave = tid >> 6, lane = tid & 63, quad = lane >> 4, l16 = lane & 15;
    const int m0 = blockIdx.x * 128, n0 = blockIdx.y * 128;
    const int wm = (wave >> 1) * 64, wn = (wave & 1) * 64;
    const int lrow = lane >> 2, lcol = (lane & 3) * 8;

    f32x4 acc[4][4] = {};

    for (int k0 = 0; k0 < EMB; k0 += 64) {
        __syncthreads();
        for (int t = 0; t < 2; t++) {
            int row = wave * 32 + t * 16 + lrow;
            load_lds16(&A[(size_t)(m0 + row) * EMB + k0 + lcol], &As0[(wave * 2 + t) * 512]);
            load_lds16(&Bt[(size_t)(n0 + row) * EMB + k0 + lcol], &Bs0[(wave * 2 + t) * 512]);
            load_lds16(&A[(size_t)(m0 + row) * EMB + k0 + 32 + lcol], &As1[(wave * 2 + t) * 512]);
            load_lds16(&Bt[(size_t)(n0 + row) * EMB + k0 + 32 + lcol], &Bs1[(wave * 2 + t) * 512]);
        }
        __syncthreads();
        {
            short8 a[4], b[4];
            for (int i = 0; i < 4; i++)
                a[i] = *(const short8*)&As0[(wm + i * 16 + l16) * 32 + quad * 8];
            for (int i = 0; i < 4; i++)
                b[i] = *(const short8*)&Bs0[(wn + i * 16 + l16) * 32 + quad * 8];
            for (int i = 0; i < 4; i++)
                for (int j = 0; j < 4; j++) acc[i][j] = mfma32(a[i], b[j], acc[i][j]);
        }
        {
            short8 a[4], b[4];
            for (int i = 0; i < 4; i++)
                a[i] = *(const short8*)&As1[(wm + i * 16 + l16) * 32 + quad * 8];
            for (int i = 0; i < 4; i++)
                b[i] = *(const short8*)&Bs1[(wn + i * 16 + l16) * 32 + quad * 8];
            for (int i = 0; i < 4; i++)
                for (int j = 0; j < 4; j++) acc[i][j] = mfma32(a[i], b[j], acc[i][j]);
        }
    }

    const int z = n0 / EMB;  // block-uniform: 0=Q, 1=K, 2=V
    if (z < 2) {
        const float* bias = z ? b1p : b0p;
        const float sc = z ? 1.0f : QSCALE;
        for (int i = 0; i < 4; i++)
            for (int j = 0; j < 4; j++) {
                int mbase = m0 + wm + i * 16 + quad * 4;
                int n = n0 + wn + j * 16 + l16;  // 0..1535 natural col
                float bv = bias[n - z * EMB];
                for (int r = 0; r < 4; r++)
                    QKb[(size_t)(mbase + r) * 1536 + n] = f2bf((acc[i][j][r] + bv) * sc);
            }
    } else {
        const int nn = n0 + wn + l16 - 2 * EMB;
        for (int j = 0; j < 4; j++) {
            __syncthreads();
            const float bv = b2p[nn + j * 16];
            const int nloc = (wave & 1) * 16 + l16;
            for (int i = 0; i < 4; i++) {
                ushort4 pk;
                pk.x = f2bf(acc[i][j][0] + bv);
                pk.y = f2bf(acc[i][j][1] + bv);
                pk.z = f2bf(acc[i][j][2] + bv);
                pk.w = f2bf(acc[i][j][3] + bv);
                *(ushort4*)&SMEM[nloc * 136 + wm + i * 16 + quad * 4] = pk;
            }
            __syncthreads();
            const int nl = tid >> 3, c = tid & 7;
            const int ng = (nl >> 4) * 64 + j * 16 + (nl & 15) + n0 - 2 * EMB;
            const int hh = ng >> 6, dd = ng & 63;
            unsigned short* dst = &Vtb[(size_t)(hh * HD + dd) * SEQ + m0];
            *(uint4*)&dst[c * 8] = *(uint4*)&SMEM[nl * 136 + c * 8];
            *(uint4*)&dst[64 + c * 8] = *(uint4*)&SMEM[nl * 136 + 64 + c * 8];
        }
    }
}

// ---------------------------------------------------------------- 64x128 out-proj GEMM
__global__ __launch_bounds__(256) void gemm_out(const unsigned short* __restrict__ A,
                                                const unsigned short* __restrict__ Bt,
                                                const float* __restrict__ bias,
                                                float* __restrict__ outp) {
    __shared__ __align__(16) unsigned short SMEM[12288];  // 24 KB
    unsigned short* As0 = SMEM;
    unsigned short* As1 = SMEM + 2048;
    unsigned short* Bs0 = SMEM + 4096;
    unsigned short* Bs1 = SMEM + 8192;
    const int tid = threadIdx.x;
    const int wave = tid >> 6, lane = tid & 63, quad = lane >> 4, l16 = lane & 15;
    const int m0 = blockIdx.x * 64, n0 = blockIdx.y * 128;
    const int wm = (wave >> 1) * 32, wn = (wave & 1) * 64;
    const int lrow = lane >> 2, lcol = (lane & 3) * 8;

    f32x4 acc[2][4] = {};

    for (int k0 = 0; k0 < EMB; k0 += 64) {
        __syncthreads();
        load_lds16(&A[(size_t)(m0 + wave * 16 + lrow) * EMB + k0 + lcol], &As0[wave * 512]);
        load_lds16(&A[(size_t)(m0 + wave * 16 + lrow) * EMB + k0 + 32 + lcol], &As1[wave * 512]);
        for (int t = 0; t < 2; t++) {
            int row = wave * 32 + t * 16 + lrow;
            load_lds16(&Bt[(size_t)(n0 + row) * EMB + k0 + lcol], &Bs0[(wave * 2 + t) * 512]);
            load_lds16(&Bt[(size_t)(n0 + row) * EMB + k0 + 32 + lcol], &Bs1[(wave * 2 + t) * 512]);
        }
        __syncthreads();
        {
            short8 a[2], b[4];
            for (int i = 0; i < 2; i++)
                a[i] = *(const short8*)&As0[(wm + i * 16 + l16) * 32 + quad * 8];
            for (int j = 0; j < 4; j++)
                b[j] = *(const short8*)&Bs0[(wn + j * 16 + l16) * 32 + quad * 8];
            for (int i = 0; i < 2; i++)
                for (int j = 0; j < 4; j++) acc[i][j] = mfma32(a[i], b[j], acc[i][j]);
        }
        {
            short8 a[2], b[4];
            for (int i = 0; i < 2; i++)
                a[i] = *(const short8*)&As1[(wm + i * 16 + l16) * 32 + quad * 8];
            for (int j = 0; j < 4; j++)
                b[j] = *(const short8*)&Bs1[(wn + j * 16 + l16) * 32 + quad * 8];
            for (int i = 0; i < 2; i++)
                for (int j = 0; j < 4; j++) acc[i][j] = mfma32(a[i], b[j], acc[i][j]);
        }
    }

    for (int i = 0; i < 2; i++)
        for (int j = 0; j < 4; j++) {
            int mbase = m0 + wm + i * 16 + quad * 4;
            int n = n0 + wn + j * 16 + l16;
            float bv = bias[n];
            for (int r = 0; r < 4; r++) outp[(size_t)(mbase + r) * EMB + n] = acc[i][j][r] + bv;
        }
}

// ---------------------------------------------------------------- attention
// 1080 blocks = 12 heads x 90 chunks; 256 threads = 4 waves over a 128-q tile.
// Each wave owns TWO 16-q groups (q, q+64); K-frags are loaded once per nt and
// serve both groups, V-frags serve both -> LDS read bytes per (q,k) halved vs
// R8. No launch_bounds min-waves cap (R7's spill lesson). Chunks <= 14 k-tiles,
// partials (696 x 16 KB) live in d_out (dead until gemm_out).
__global__ __launch_bounds__(256) void attn_kernel(const unsigned short* __restrict__ QKb,
                                                   const unsigned short* __restrict__ Vtb,
                                                   unsigned short* __restrict__ ctxb,
                                                   unsigned short* __restrict__ Op,
                                                   float* __restrict__ mArr,
                                                   float* __restrict__ lArr) {
    __shared__ __align__(16) unsigned short Ks[64 * 64];
    __shared__ __align__(16) unsigned short Vs[64 * 64];

    const int bid = blockIdx.x;
    const int h = bid % HEADS;
    int idx = bid / HEADS;  // 0..89, 0 = longest (i128=31) first
    int i128 = 0, ch = 0, nch = 1;
    for (int i = 31; i >= 0; --i) {
        int nc = NCH(i);
        if (idx < nc) { i128 = i; ch = idx; nch = nc; break; }
        idx -= nc;
    }
    const int T = 2 * i128 + 2;
    const int kb = ch * T / nch;
    const int ke = (ch + 1) * T / nch - 1;
    const int qbase = i128 * 128;
    const int tid = threadIdx.x;
    const int wave = tid >> 6, lane = tid & 63, quad = lane >> 4, l16 = lane & 15;

    const unsigned short* Qg = QKb + (size_t)h * HD;          // row stride 1536
    const unsigned short* Kg = QKb + (size_t)(EMB + h * HD);  // row stride 1536
    const unsigned short* Vh = Vtb + (size_t)h * HD * SEQ;    // [d][m]

    const int q0 = qbase + wave * 16 + l16;
    const int q1 = q0 + 64;
    const short8 bQ00 = *(const short8*)&Qg[(size_t)q0 * 1536 + quad * 8];
    const short8 bQ01 = *(const short8*)&Qg[(size_t)q0 * 1536 + 32 + quad * 8];
    const short8 bQ10 = *(const short8*)&Qg[(size_t)q1 * 1536 + quad * 8];
    const short8 bQ11 = *(const short8*)&Qg[(size_t)q1 * 1536 + 32 + quad * 8];

    const int row = tid >> 2, t4 = tid & 3, cg = t4 * 16;
    const int swk = row & 7, swv = row & 15;

    f32x4 O0[4] = {}, O1[4] = {};
    float m0i = -3.0e38f, l0i = 0.f, m1i = -3.0e38f, l1i = 0.f;

    uint4 kr0, kr1, vr0, vr1;
    {
        const int kb64 = kb * 64;
        kr0 = *(const uint4*)&Kg[(size_t)(kb64 + row) * 1536 + cg];
        kr1 = *(const uint4*)&Kg[(size_t)(kb64 + row) * 1536 + cg + 8];
        vr0 = *(const uint4*)&Vh[(size_t)row * SEQ + kb64 + cg];
        vr1 = *(const uint4*)&Vh[(size_t)row * SEQ + kb64 + cg + 8];
    }

    for (int kt = kb; kt <= ke; kt++) {
        const int kbase = kt * 64;
        __syncthreads();
        *(uint4*)&Ks[row * 64 + ((2 * t4) ^ swk) * 8] = kr0;
        *(uint4*)&Ks[row * 64 + ((2 * t4 + 1) ^ swk) * 8] = kr1;
        *(uint2*)&Vs[row * 64 + ((4 * t4) ^ swv) * 4] = ((const uint2*)&vr0)[0];
        *(uint2*)&Vs[row * 64 + ((4 * t4 + 1) ^ swv) * 4] = ((const uint2*)&vr0)[1];
        *(uint2*)&Vs[row * 64 + ((4 * t4 + 2) ^ swv) * 4] = ((const uint2*)&vr1)[0];
        *(uint2*)&Vs[row * 64 + ((4 * t4 + 3) ^ swv) * 4] = ((const uint2*)&vr1)[1];
        if (kt < ke) {
            const int nb = kbase + 64;
            kr0 = *(const uint4*)&Kg[(size_t)(nb + row) * 1536 + cg];
            kr1 = *(const uint4*)&Kg[(size_t)(nb + row) * 1536 + cg + 8];
            vr0 = *(const uint4*)&Vh[(size_t)row * SEQ + nb + cg];
            vr1 = *(const uint4*)&Vh[(size_t)row * SEQ + nb + cg + 8];
        }
        __syncthreads();

        // group 0 (rows q0) fully masked for this wave? (wave-uniform)
        const bool g0act = (kbase <= qbase + wave * 16 + 15);

        // S^T: lane holds q=l16 (col), k=kbase+nt*16+quad*4+r (row).
        // K-frags loaded once, used for BOTH q-groups.
        const int swr = l16 & 7;
        f32x4 st0[4], st1[4];
        for (int nt = 0; nt < 4; nt++) {
            short8 aK0 = *(const short8*)&Ks[(nt * 16 + l16) * 64 + (quad ^ swr) * 8];
            short8 aK1 = *(const short8*)&Ks[(nt * 16 + l16) * 64 + ((quad + 4) ^ swr) * 8];
            f32x4 z1 = {};
            z1 = mfma32(aK0, bQ10, z1);
            z1 = mfma32(aK1, bQ11, z1);
            st1[nt] = z1;
            if (g0act) {
                f32x4 z0 = {};
                z0 = mfma32(aK0, bQ00, z0);
                z0 = mfma32(aK1, bQ01, z0);
                st0[nt] = z0;
            }
        }
        if (kbase + 63 > qbase + 64 + wave * 16) {  // group-1 diagonal tile
            for (int nt = 0; nt < 4; nt++)
                for (int r = 0; r < 4; r++)
                    if (kbase + nt * 16 + quad * 4 + r > q1) st1[nt][r] = -INFINITY;
        }
        if (g0act && kbase + 63 > qbase + wave * 16) {  // group-0 diagonal tile
            for (int nt = 0; nt < 4; nt++)
                for (int r = 0; r < 4; r++)
                    if (kbase + nt * 16 + quad * 4 + r > q0) st0[nt][r] = -INFINITY;
        }

        short4v pk0[4], pk1[4];
        softmax_step(st1, m1i, l1i, O1, pk1);
        if (g0act) softmax_step(st0, m0i, l0i, O0, pk0);

        // O^T += V^T P^T : each V-frag read serves both q-groups
        for (int dt = 0; dt < 4; dt++)
            for (int nt = 0; nt < 4; nt++) {
                short4v av =
                    *(const short4v*)&Vs[(dt * 16 + l16) * 64 + ((4 * nt + quad) ^ l16) * 4];
                O1[dt] = mfma16(av, pk1[nt], O1[dt]);
                if (g0act) O0[dt] = mfma16(av, pk0[nt], O0[dt]);
            }
    }

    // epilogue per group
    for (int g = 0; g < 2; g++) {
        f32x4* O = g ? O1 : O0;
        const float mi = g ? m1i : m0i;
        const float li = g ? l1i : l0i;
        const int qglob = g ? q1 : q0;
        const int ql = g * 64 + wave * 16 + l16;  // 0..127
        if (nch == 1) {
            const float inv = 1.f / li;
            for (int dt = 0; dt < 4; dt++) {
                ushort4 o;
                o.x = f2bf(O[dt][0] * inv);
                o.y = f2bf(O[dt][1] * inv);
                o.z = f2bf(O[dt][2] * inv);
                o.w = f2bf(O[dt][3] * inv);
                *(ushort4*)&ctxb[(size_t)qglob * EMB + h * HD + dt * 16 + quad * 4] = o;
            }
        } else {
            if (ch == 0) {
                for (int dt = 0; dt < 4; dt++) {
                    ushort4 o;
                    o.x = f2bf(O[dt][0]);
                    o.y = f2bf(O[dt][1]);
                    o.z = f2bf(O[dt][2]);
                    o.w = f2bf(O[dt][3]);
                    *(ushort4*)&ctxb[(size_t)qglob * EMB + h * HD + dt * 16 + quad * 4] = o;
                }
            } else {
                const int pid = pid_base(h, i128) + (ch - 1);
                for (int dt = 0; dt < 4; dt++) {
                    ushort4 o;
                    o.x = f2bf(O[dt][0]);
                    o.y = f2bf(O[dt][1]);
                    o.z = f2bf(O[dt][2]);
                    o.w = f2bf(O[dt][3]);
                    *(ushort4*)&Op[(size_t)pid * 8192 + ql * 64 + dt * 16 + quad * 4] = o;
                }
            }
            if (quad == 0) {
                const int mli = ((h * 32 + i128) * 5 + ch) * 128 + ql;
                mArr[mli] = mi;
                lArr[mli] = li;
            }
        }
    }
}

// ---------------------------------------------------------------- merge (i128>=7)
__global__ __launch_bounds__(256) void merge_kernel(const unsigned short* __restrict__ Op,
                                                    const float* __restrict__ mArr,
                                                    const float* __restrict__ lArr,
                                                    unsigned short* __restrict__ ctxb) {
    const int gid = blockIdx.x;  // 0..299
    const int h = gid % HEADS;
    const int i128 = 7 + gid / HEADS;
    const int nch = NCH(i128);  // 2..5
    const int q = threadIdx.x >> 1, d0 = (threadIdx.x & 1) * 32;
    const int mlbase = (h * 32 + i128) * 5;

    float mc[5], lc[5];
    for (int c = 0; c < nch; c++) {
        mc[c] = mArr[(mlbase + c) * 128 + q];
        lc[c] = lArr[(mlbase + c) * 128 + q];
    }
    float M = mc[0];
    for (int c = 1; c < nch; c++) M = fmaxf(M, mc[c]);
    float w[5], L = 0.f;
    for (int c = 0; c < nch; c++) {
        w[c] = __builtin_amdgcn_exp2f(mc[c] - M);
        L += w[c] * lc[c];
    }
    const float inv = 1.f / L;
    for (int c = 0; c < nch; c++) w[c] *= inv;

    const int pb = pid_base(h, i128);
    unsigned short* dst = &ctxb[(size_t)(i128 * 128 + q) * EMB + h * HD + d0];
    for (int jj = 0; jj < 32; jj += 8) {
        uint4 u0 = *(const uint4*)&dst[jj];  // chunk0 (unnormalized) in place
        float f[8];
        const unsigned short* p0 = (const unsigned short*)&u0;
        for (int t = 0; t < 8; t++)
            f[t] = w[0] * __builtin_bit_cast(float, (unsigned int)p0[t] << 16);
        for (int c = 1; c < nch; c++) {
            uint4 u = *(const uint4*)&Op[(size_t)(pb + c - 1) * 8192 + q * 64 + d0 + jj];
            const unsigned short* p = (const unsigned short*)&u;
            for (int t = 0; t < 8; t++)
                f[t] += w[c] * __builtin_bit_cast(float, (unsigned int)p[t] << 16);
        }
        unsigned short o[8];
        for (int t = 0; t < 8; t++) o[t] = f2bf(f[t]);
        *(uint4*)&dst[jj] = *(uint4*)o;
    }
}

// ---------------------------------------------------------------- launch
extern "C" void kernel_launch(void* const* d_in, const int* in_sizes, int n_in,
                              void* d_out, int out_size, void* d_ws, size_t ws_size,
                              hipStream_t stream) {
    const float* x = (const float*)d_in[0];
    const float* wq = (const float*)d_in[1];
    const float* bq = (const float*)d_in[2];
    const float* wk = (const float*)d_in[3];
    const float* bk = (const float*)d_in[4];
    const float* wv = (const float*)d_in[5];
    const float* bv = (const float*)d_in[6];
    const float* wo = (const float*)d_in[7];
    const float* bo = (const float*)d_in[8];

    unsigned short* ws = (unsigned short*)d_ws;
    unsigned short* xb = ws;                          // 3,145,728 ush
    unsigned short* wqkvT = xb + SEQ * EMB;           // 1,769,472
    unsigned short* woT = wqkvT + 3 * EMB * EMB;      // 589,824
    unsigned short* QKb = woT + EMB * EMB;            // 4096*1536
    unsigned short* Vtb = QKb + (size_t)SEQ * 1536;   // 3,145,728
    unsigned short* ctxb = Vtb + HEADS * SEQ * HD;    // 3,145,728
    // attn-phase: O-partials live in d_out (696 pids x 8192 ush = 11.4 MB,
    // dead until gemm_out rewrites it); m/l arrays alias dead xb.
    unsigned short* Op = (unsigned short*)d_out;
    float* mArr = (float*)ws;                         // 245,760 f32
    float* lArr = mArr + 245760;                      // 245,760 f32 (within xb)

    convert_all<<<dim3(3072 + 576), 256, 0, stream>>>(x, wq, wk, wv, wo, xb, wqkvT, woT);
    gemm_qkv<<<dim3(SEQ / 128, 3 * EMB / 128), 256, 0, stream>>>(
        xb, wqkvT, bq, bk, bv, QKb, Vtb);
    attn_kernel<<<dim3(12 * 90), 256, 0, stream>>>(QKb, Vtb, ctxb, Op, mArr, lArr);
    merge_kernel<<<dim3(300), 256, 0, stream>>>(Op, mArr, lArr, ctxb);
    gemm_out<<<dim3(SEQ / 64, EMB / 128), 256, 0, stream>>>(ctxb, woT, bo, (float*)d_out);
}

// Round 10
// 194.774 us; speedup vs baseline: 1.1711x; 1.1711x over previous
//
#include <hip/hip_runtime.h>
#include <stdint.h>

#define SEQ 4096
#define EMB 768
#define HEADS 12
#define HD 64

typedef __attribute__((ext_vector_type(8))) short short8;
typedef __attribute__((ext_vector_type(4))) short short4v;
typedef __attribute__((ext_vector_type(8))) __bf16 bf16x8;
typedef __attribute__((ext_vector_type(4))) __bf16 bf16x4;
typedef __attribute__((ext_vector_type(4))) float f32x4;

// scale * log2(e) folded into Q: (1/sqrt(64)) * 1.4426950408889634
#define QSCALE 0.18033688011112043f

static __device__ __forceinline__ unsigned short f2bf(float f) {
    unsigned int u = __builtin_bit_cast(unsigned int, f);
    unsigned int r = 0x7fffu + ((u >> 16) & 1u);
    u += r;
    return (unsigned short)(u >> 16);
}

static __device__ __forceinline__ f32x4 mfma32(short8 a, short8 b, f32x4 c) {
    return __builtin_amdgcn_mfma_f32_16x16x32_bf16(
        __builtin_bit_cast(bf16x8, a), __builtin_bit_cast(bf16x8, b), c, 0, 0, 0);
}

static __device__ __forceinline__ f32x4 mfma16(short4v a, short4v b, f32x4 c) {
#if __has_builtin(__builtin_amdgcn_mfma_f32_16x16x16_bf16)
    return __builtin_amdgcn_mfma_f32_16x16x16_bf16(
        __builtin_bit_cast(bf16x4, a), __builtin_bit_cast(bf16x4, b), c, 0, 0, 0);
#else
    return __builtin_amdgcn_mfma_f32_16x16x16bf16_1k(a, b, c, 0, 0, 0);
#endif
}

static __device__ __forceinline__ short4v pack4bf(float a, float b, float c, float d) {
#if __has_builtin(__builtin_amdgcn_cvt_pk_bf16_f32)
    typedef __attribute__((ext_vector_type(2))) __bf16 bf16x2;
    bf16x2 lo = __builtin_amdgcn_cvt_pk_bf16_f32(a, b);
    bf16x2 hi = __builtin_amdgcn_cvt_pk_bf16_f32(c, d);
    uint2 u = {__builtin_bit_cast(unsigned int, lo), __builtin_bit_cast(unsigned int, hi)};
    return __builtin_bit_cast(short4v, u);
#else
    short4v p;
    p[0] = (short)f2bf(a); p[1] = (short)f2bf(b);
    p[2] = (short)f2bf(c); p[3] = (short)f2bf(d);
    return p;
#endif
}

static __device__ __forceinline__ void load_lds16(const void* g, void* l) {
    __builtin_amdgcn_global_load_lds(
        (const __attribute__((address_space(1))) unsigned int*)(uintptr_t)g,
        (__attribute__((address_space(3))) unsigned int*)(uintptr_t)l, 16, 0, 0);
}

// partial-id for (h, i128, ch>=1); 36 slots/head, 432 total (R8 scheme)
static __device__ __forceinline__ int pid_of(int h, int i128, int ch) {
    int b = (i128 < 20) ? (i128 - 10)
                        : (i128 < 30 ? 10 + (i128 - 20) * 2 : 30 + (i128 - 30) * 3);
    return h * 36 + b + (ch - 1);
}

// online-softmax step over one 64-k tile held as st[4] (S^T layout)
static __device__ __forceinline__ void softmax_step(f32x4* st, float& m_i, float& l_i,
                                                    f32x4* O, short4v* pk) {
    float mx = -3.0e38f;
    for (int nt = 0; nt < 4; nt++)
        for (int r = 0; r < 4; r++) mx = fmaxf(mx, st[nt][r]);
    mx = fmaxf(mx, __shfl_xor(mx, 16));
    mx = fmaxf(mx, __shfl_xor(mx, 32));
    const bool inc = mx > m_i;
    if (__ballot(inc)) {
        const float mn = inc ? mx : m_i;
        const float alpha = __builtin_amdgcn_exp2f(m_i - mn);
        m_i = mn;
        l_i *= alpha;
        for (int dt = 0; dt < 4; dt++)
            for (int r = 0; r < 4; r++) O[dt][r] *= alpha;
    }
    float rs = 0.f;
    for (int nt = 0; nt < 4; nt++) {
        float p0 = __builtin_amdgcn_exp2f(st[nt][0] - m_i);
        float p1 = __builtin_amdgcn_exp2f(st[nt][1] - m_i);
        float p2 = __builtin_amdgcn_exp2f(st[nt][2] - m_i);
        float p3 = __builtin_amdgcn_exp2f(st[nt][3] - m_i);
        rs += p0 + p1 + p2 + p3;
        pk[nt] = pack4bf(p0, p1, p2, p3);
    }
    rs += __shfl_xor(rs, 16);
    rs += __shfl_xor(rs, 32);
    l_i += rs;
}

// ---------------------------------------------------------------- fused convert
__global__ __launch_bounds__(256) void convert_all(const float* __restrict__ x,
                                                   const float* __restrict__ wq,
                                                   const float* __restrict__ wk,
                                                   const float* __restrict__ wv,
                                                   const float* __restrict__ wo,
                                                   unsigned short* __restrict__ xb,
                                                   unsigned short* __restrict__ wqkvT,
                                                   unsigned short* __restrict__ woT) {
    __shared__ float Ls[64][65];
    const int bid = blockIdx.x;
    if (bid < 3072) {
        int i = bid * 256 + threadIdx.x;
        float4 v = ((const float4*)x)[i];
        ushort4 o = {f2bf(v.x), f2bf(v.y), f2bf(v.z), f2bf(v.w)};
        ((ushort4*)xb)[i] = o;
        return;
    }
    const int idx = bid - 3072;
    const int z = idx / 144;
    const int bx = (idx % 144) / 12, by = idx % 12;
    const float* W = (z == 0) ? wq : (z == 1) ? wk : (z == 2) ? wv : wo;
    unsigned short* dst = (z < 3) ? (wqkvT + (size_t)z * EMB * EMB) : woT;
    const int k0 = bx * 64, n0 = by * 64;
    const int r = threadIdx.x >> 2, c0 = (threadIdx.x & 3) * 16;
    for (int j = 0; j < 16; j += 4) {
        float4 v = *(const float4*)&W[(size_t)(k0 + r) * EMB + n0 + c0 + j];
        Ls[r][c0 + j] = v.x;
        Ls[r][c0 + j + 1] = v.y;
        Ls[r][c0 + j + 2] = v.z;
        Ls[r][c0 + j + 3] = v.w;
    }
    __syncthreads();
    unsigned short tmp[16];
    for (int j = 0; j < 16; j++) tmp[j] = f2bf(Ls[c0 + j][r]);
    *(uint4*)&dst[(size_t)(n0 + r) * EMB + k0 + c0] = *(uint4*)tmp;
    *(uint4*)&dst[(size_t)(n0 + r) * EMB + k0 + c0 + 8] = *(uint4*)(tmp + 8);
}

// ---------------------------------------------------------------- 128x128 QKV GEMM
// Single-barrier double-buffered BK=32 staging via global_load_lds DMA.
__global__ __launch_bounds__(256) void gemm_qkv(const unsigned short* __restrict__ A,
                                                const unsigned short* __restrict__ Bt,
                                                const float* __restrict__ b0p,
                                                const float* __restrict__ b1p,
                                                const float* __restrict__ b2p,
                                                unsigned short* __restrict__ QKb,
                                                unsigned short* __restrict__ Vtb) {
    __shared__ __align__(16) unsigned short SMEM[16384];  // [buf*8192]: As 4096 | Bs 4096
    const int tid = threadIdx.x;
    const int wave = tid >> 6, lane = tid & 63, quad = lane >> 4, l16 = lane & 15;
    const int m0 = blockIdx.x * 128, n0 = blockIdx.y * 128;
    const int wm = (wave >> 1) * 64, wn = (wave & 1) * 64;
    const int lrow = lane >> 2, lcol = (lane & 3) * 8;

    f32x4 acc[4][4] = {};

    // preload k0 = 0 into buf 0
    for (int t = 0; t < 2; t++) {
        int row = wave * 32 + t * 16 + lrow;
        load_lds16(&A[(size_t)(m0 + row) * EMB + lcol], &SMEM[(wave * 2 + t) * 512]);
        load_lds16(&Bt[(size_t)(n0 + row) * EMB + lcol], &SMEM[4096 + (wave * 2 + t) * 512]);
    }
    int buf = 0;
    for (int k0 = 0; k0 < EMB; k0 += 32) {
        __syncthreads();  // drains this buf's DMA; other buf free
        if (k0 + 32 < EMB) {
            unsigned short* A_ = &SMEM[(buf ^ 1) * 8192];
            unsigned short* B_ = A_ + 4096;
            for (int t = 0; t < 2; t++) {
                int row = wave * 32 + t * 16 + lrow;
                load_lds16(&A[(size_t)(m0 + row) * EMB + k0 + 32 + lcol], &A_[(wave * 2 + t) * 512]);
                load_lds16(&Bt[(size_t)(n0 + row) * EMB + k0 + 32 + lcol], &B_[(wave * 2 + t) * 512]);
            }
        }
        const unsigned short* A_ = &SMEM[buf * 8192];
        const unsigned short* B_ = A_ + 4096;
        short8 a[4], b[4];
        for (int i = 0; i < 4; i++) a[i] = *(const short8*)&A_[(wm + i * 16 + l16) * 32 + quad * 8];
        for (int i = 0; i < 4; i++) b[i] = *(const short8*)&B_[(wn + i * 16 + l16) * 32 + quad * 8];
        for (int i = 0; i < 4; i++)
            for (int j = 0; j < 4; j++) acc[i][j] = mfma32(a[i], b[j], acc[i][j]);
        buf ^= 1;
    }

    const int z = n0 / EMB;  // block-uniform: 0=Q, 1=K, 2=V
    if (z < 2) {
        const float* bias = z ? b1p : b0p;
        const float sc = z ? 1.0f : QSCALE;
        for (int i = 0; i < 4; i++)
            for (int j = 0; j < 4; j++) {
                int mbase = m0 + wm + i * 16 + quad * 4;
                int n = n0 + wn + j * 16 + l16;  // 0..1535 natural col
                float bv = bias[n - z * EMB];
                for (int r = 0; r < 4; r++)
                    QKb[(size_t)(mbase + r) * 1536 + n] = f2bf((acc[i][j][r] + bv) * sc);
            }
    } else {
        const int nn = n0 + wn + l16 - 2 * EMB;
        for (int j = 0; j < 4; j++) {
            __syncthreads();
            const float bv = b2p[nn + j * 16];
            const int nloc = (wave & 1) * 16 + l16;
            for (int i = 0; i < 4; i++) {
                ushort4 pk;
                pk.x = f2bf(acc[i][j][0] + bv);
                pk.y = f2bf(acc[i][j][1] + bv);
                pk.z = f2bf(acc[i][j][2] + bv);
                pk.w = f2bf(acc[i][j][3] + bv);
                *(ushort4*)&SMEM[nloc * 136 + wm + i * 16 + quad * 4] = pk;
            }
            __syncthreads();
            const int nl = tid >> 3, c = tid & 7;
            const int ng = (nl >> 4) * 64 + j * 16 + (nl & 15) + n0 - 2 * EMB;
            const int hh = ng >> 6, dd = ng & 63;
            unsigned short* dst = &Vtb[(size_t)(hh * HD + dd) * SEQ + m0];
            *(uint4*)&dst[c * 8] = *(uint4*)&SMEM[nl * 136 + c * 8];
            *(uint4*)&dst[64 + c * 8] = *(uint4*)&SMEM[nl * 136 + 64 + c * 8];
        }
    }
}

// ---------------------------------------------------------------- 64x128 out-proj GEMM
// Same single-barrier dbuf-DMA staging.
__global__ __launch_bounds__(256) void gemm_out(const unsigned short* __restrict__ A,
                                                const unsigned short* __restrict__ Bt,
                                                const float* __restrict__ bias,
                                                float* __restrict__ outp) {
    __shared__ __align__(16) unsigned short SMEM[12288];  // As[2]@0/2048, Bs[2]@4096/8192
    const int tid = threadIdx.x;
    const int wave = tid >> 6, lane = tid & 63, quad = lane >> 4, l16 = lane & 15;
    const int m0 = blockIdx.x * 64, n0 = blockIdx.y * 128;
    const int wm = (wave >> 1) * 32, wn = (wave & 1) * 64;
    const int lrow = lane >> 2, lcol = (lane & 3) * 8;

    f32x4 acc[2][4] = {};

    load_lds16(&A[(size_t)(m0 + wave * 16 + lrow) * EMB + lcol], &SMEM[wave * 512]);
    for (int t = 0; t < 2; t++) {
        int row = wave * 32 + t * 16 + lrow;
        load_lds16(&Bt[(size_t)(n0 + row) * EMB + lcol], &SMEM[4096 + (wave * 2 + t) * 512]);
    }
    int buf = 0;
    for (int k0 = 0; k0 < EMB; k0 += 32) {
        __syncthreads();
        if (k0 + 32 < EMB) {
            unsigned short* A_ = &SMEM[(buf ^ 1) * 2048];
            unsigned short* B_ = &SMEM[4096 + (buf ^ 1) * 4096];
            load_lds16(&A[(size_t)(m0 + wave * 16 + lrow) * EMB + k0 + 32 + lcol], &A_[wave * 512]);
            for (int t = 0; t < 2; t++) {
                int row = wave * 32 + t * 16 + lrow;
                load_lds16(&Bt[(size_t)(n0 + row) * EMB + k0 + 32 + lcol], &B_[(wave * 2 + t) * 512]);
            }
        }
        const unsigned short* A_ = &SMEM[buf * 2048];
        const unsigned short* B_ = &SMEM[4096 + buf * 4096];
        short8 a[2], b[4];
        for (int i = 0; i < 2; i++) a[i] = *(const short8*)&A_[(wm + i * 16 + l16) * 32 + quad * 8];
        for (int j = 0; j < 4; j++) b[j] = *(const short8*)&B_[(wn + j * 16 + l16) * 32 + quad * 8];
        for (int i = 0; i < 2; i++)
            for (int j = 0; j < 4; j++) acc[i][j] = mfma32(a[i], b[j], acc[i][j]);
        buf ^= 1;
    }

    for (int i = 0; i < 2; i++)
        for (int j = 0; j < 4; j++) {
            int mbase = m0 + wm + i * 16 + quad * 4;
            int n = n0 + wn + j * 16 + l16;
            float bv = bias[n];
            for (int r = 0; r < 4; r++) outp[(size_t)(mbase + r) * EMB + n] = acc[i][j][r] + bv;
        }
}

// ---------------------------------------------------------------- attention
// R8 structure (816 blocks = 12 heads x 68 chunks; 512 thr = 8 waves over a
// 128-q tile; 16 q-rows/wave, ~48 VGPR, 32 waves/CU) + single-barrier dbuf:
// K/V tiles staged by global_load_lds DMA with the XOR bank-swizzle baked into
// the per-lane GLOBAL address permutation (LDS side is rigid base+lane*16).
// One __syncthreads per iter; next-tile DMA flies during compute.
__global__ __launch_bounds__(512) void attn_kernel(const unsigned short* __restrict__ QKb,
                                                   const unsigned short* __restrict__ Vtb,
                                                   unsigned short* __restrict__ ctxb,
                                                   unsigned short* __restrict__ Op,
                                                   float* __restrict__ mArr,
                                                   float* __restrict__ lArr) {
    __shared__ __align__(16) unsigned short Ks[2][64 * 64];  // 16 KB
    __shared__ __align__(16) unsigned short Vs[2][64 * 64];  // 16 KB

    const int bid = blockIdx.x;
    const int h = bid % HEADS;
    const int r2 = 67 - bid / HEADS;  // big i128 (long chunks) first
    int i128, ch, nch;
    if (r2 < 10) {
        i128 = r2; ch = 0; nch = 1;
    } else if (r2 < 30) {
        int t = r2 - 10; i128 = 10 + (t >> 1); ch = t & 1; nch = 2;
    } else if (r2 < 60) {
        int t = r2 - 30; i128 = 20 + t / 3; ch = t % 3; nch = 3;
    } else {
        int t = r2 - 60; i128 = 30 + (t >> 2); ch = t & 3; nch = 4;
    }
    const int T = 2 * i128 + 2;
    const int kb = ch * T / nch;
    const int ke = (ch + 1) * T / nch - 1;
    const int qbase = i128 * 128;
    const int tid = threadIdx.x;
    const int wave = tid >> 6, lane = tid & 63, quad = lane >> 4, l16 = lane & 15;

    const unsigned short* Qg = QKb + (size_t)h * HD;          // row stride 1536
    const unsigned short* Kg = QKb + (size_t)(EMB + h * HD);  // row stride 1536
    const unsigned short* Vh = Vtb + (size_t)h * HD * SEQ;    // [d][m]

    const int q = qbase + wave * 16 + l16;  // waves 0..7 cover 128 q-rows
    const short8 bQ0 = *(const short8*)&Qg[(size_t)q * 1536 + quad * 8];
    const short8 bQ1 = *(const short8*)&Qg[(size_t)q * 1536 + 32 + quad * 8];

    // DMA lane mapping: wave w lane l stages row srow = w*8+(l>>3), 16B-chunk
    // sc = l&7; global chunk sg = sc ^ (srow&7) lands at LDS chunk sc (swizzle
    // via address permutation; row's 8 chunks stay in one 128B segment).
    const int srow = wave * 8 + ((lane >> 3));
    const int sg = (lane & 7) ^ (srow & 7);

    f32x4 O[4] = {};
    float m_i = -3.0e38f, l_i = 0.f;

    {
        const int kb64 = kb * 64;
        load_lds16(&Kg[(size_t)(kb64 + srow) * 1536 + sg * 8], &Ks[0][wave * 512]);
        load_lds16(&Vh[(size_t)srow * SEQ + kb64 + sg * 8], &Vs[0][wave * 512]);
    }
    int buf = 0;
    for (int kt = kb; kt <= ke; kt++) {
        const int kbase = kt * 64;
        __syncthreads();  // drains buf's DMA (publishes tile); buf^1 is free
        if (kt < ke) {
            const int nb = kbase + 64;
            load_lds16(&Kg[(size_t)(nb + srow) * 1536 + sg * 8], &Ks[buf ^ 1][wave * 512]);
            load_lds16(&Vh[(size_t)srow * SEQ + nb + sg * 8], &Vs[buf ^ 1][wave * 512]);
        }
        // wave-uniform causal skip
        if (kbase <= qbase + wave * 16 + 15) {
            // S^T tiles: lane holds q=l16 (col), k=kbase+nt*16+quad*4+r (row)
            const int swr = l16 & 7;
            f32x4 st[4];
            for (int nt = 0; nt < 4; nt++) {
                short8 aK0 = *(const short8*)&Ks[buf][(nt * 16 + l16) * 64 + (quad ^ swr) * 8];
                short8 aK1 =
                    *(const short8*)&Ks[buf][(nt * 16 + l16) * 64 + ((quad + 4) ^ swr) * 8];
                f32x4 z = {};
                z = mfma32(aK0, bQ0, z);
                z = mfma32(aK1, bQ1, z);
                st[nt] = z;
            }
            if (kbase + 63 > qbase + wave * 16) {  // diagonal tile for this wave
                for (int nt = 0; nt < 4; nt++)
                    for (int r = 0; r < 4; r++)
                        if (kbase + nt * 16 + quad * 4 + r > q) st[nt][r] = -INFINITY;
            }

            short4v pk[4];
            softmax_step(st, m_i, l_i, O, pk);

            // O^T += V^T P^T. V LDS chunk c (16B) holds global chunk c^(row&7):
            // global 8B slot j=4nt+quad -> LDS 8B slot 2*((j>>1)^swr)+(j&1).
            for (int dt = 0; dt < 4; dt++)
                for (int nt = 0; nt < 4; nt++) {
                    const int j = 4 * nt + quad;
                    short4v av = *(const short4v*)&Vs[buf][(dt * 16 + l16) * 64 +
                                                          (2 * ((j >> 1) ^ swr) + (j & 1)) * 4];
                    O[dt] = mfma16(av, pk[nt], O[dt]);
                }
        }
        buf ^= 1;
    }

    const int ql = wave * 16 + l16;  // 0..127
    if (nch == 1) {
        const float inv = 1.f / l_i;
        for (int dt = 0; dt < 4; dt++) {
            ushort4 o;
            o.x = f2bf(O[dt][0] * inv);
            o.y = f2bf(O[dt][1] * inv);
            o.z = f2bf(O[dt][2] * inv);
            o.w = f2bf(O[dt][3] * inv);
            *(ushort4*)&ctxb[(size_t)q * EMB + h * HD + dt * 16 + quad * 4] = o;
        }
    } else {
        if (ch == 0) {
            for (int dt = 0; dt < 4; dt++) {
                ushort4 o;
                o.x = f2bf(O[dt][0]);
                o.y = f2bf(O[dt][1]);
                o.z = f2bf(O[dt][2]);
                o.w = f2bf(O[dt][3]);
                *(ushort4*)&ctxb[(size_t)q * EMB + h * HD + dt * 16 + quad * 4] = o;
            }
        } else {
            const int pid = pid_of(h, i128, ch);
            for (int dt = 0; dt < 4; dt++) {
                ushort4 o;
                o.x = f2bf(O[dt][0]);
                o.y = f2bf(O[dt][1]);
                o.z = f2bf(O[dt][2]);
                o.w = f2bf(O[dt][3]);
                *(ushort4*)&Op[(size_t)pid * 8192 + ql * 64 + dt * 16 + quad * 4] = o;
            }
        }
        if (quad == 0) {
            const int mli = ((h * 32 + i128) * 4 + ch) * 128 + ql;
            mArr[mli] = m_i;
            lArr[mli] = l_i;
        }
    }
}

// ---------------------------------------------------------------- merge (i128>=10)
__global__ __launch_bounds__(256) void merge_kernel(const unsigned short* __restrict__ Op,
                                                    const float* __restrict__ mArr,
                                                    const float* __restrict__ lArr,
                                                    unsigned short* __restrict__ ctxb) {
    const int gid = blockIdx.x;  // 0..263
    const int h = gid % HEADS;
    const int i128 = 10 + gid / HEADS;
    const int nch = (i128 < 20) ? 2 : (i128 < 30) ? 3 : 4;
    const int q = threadIdx.x >> 1, d0 = (threadIdx.x & 1) * 32;
    const int mlbase = (h * 32 + i128) * 4;

    float mc[4], lc[4];
    for (int c = 0; c < nch; c++) {
        mc[c] = mArr[(mlbase + c) * 128 + q];
        lc[c] = lArr[(mlbase + c) * 128 + q];
    }
    float M = mc[0];
    for (int c = 1; c < nch; c++) M = fmaxf(M, mc[c]);
    float w[4], L = 0.f;
    for (int c = 0; c < nch; c++) {
        w[c] = __builtin_amdgcn_exp2f(mc[c] - M);
        L += w[c] * lc[c];
    }
    const float inv = 1.f / L;
    for (int c = 0; c < nch; c++) w[c] *= inv;

    unsigned short* dst = &ctxb[(size_t)(i128 * 128 + q) * EMB + h * HD + d0];
    for (int jj = 0; jj < 32; jj += 8) {
        uint4 u0 = *(const uint4*)&dst[jj];  // chunk0 (unnormalized) in place
        float f[8];
        const unsigned short* p0 = (const unsigned short*)&u0;
        for (int t = 0; t < 8; t++)
            f[t] = w[0] * __builtin_bit_cast(float, (unsigned int)p0[t] << 16);
        for (int c = 1; c < nch; c++) {
            const int pid = pid_of(h, i128, c);
            uint4 u = *(const uint4*)&Op[(size_t)pid * 8192 + q * 64 + d0 + jj];
            const unsigned short* p = (const unsigned short*)&u;
            for (int t = 0; t < 8; t++)
                f[t] += w[c] * __builtin_bit_cast(float, (unsigned int)p[t] << 16);
        }
        unsigned short o[8];
        for (int t = 0; t < 8; t++) o[t] = f2bf(f[t]);
        *(uint4*)&dst[jj] = *(uint4*)o;
    }
}

// ---------------------------------------------------------------- launch
extern "C" void kernel_launch(void* const* d_in, const int* in_sizes, int n_in,
                              void* d_out, int out_size, void* d_ws, size_t ws_size,
                              hipStream_t stream) {
    const float* x = (const float*)d_in[0];
    const float* wq = (const float*)d_in[1];
    const float* bq = (const float*)d_in[2];
    const float* wk = (const float*)d_in[3];
    const float* bk = (const float*)d_in[4];
    const float* wv = (const float*)d_in[5];
    const float* bv = (const float*)d_in[6];
    const float* wo = (const float*)d_in[7];
    const float* bo = (const float*)d_in[8];

    unsigned short* ws = (unsigned short*)d_ws;
    unsigned short* xb = ws;                          // 3,145,728 ush
    unsigned short* wqkvT = xb + SEQ * EMB;           // 1,769,472
    unsigned short* woT = wqkvT + 3 * EMB * EMB;      // 589,824
    unsigned short* QKb = woT + EMB * EMB;            // 4096*1536
    unsigned short* Vtb = QKb + (size_t)SEQ * 1536;   // 3,145,728
    unsigned short* ctxb = Vtb + HEADS * SEQ * HD;    // 3,145,728
    // attn-phase scratch aliases xb+wqkvT (dead after gemm_qkv):
    // Op 432*8192 = 3,538,944 ush; mArr/lArr 196,608 f32 each -> ends 4,325,376
    unsigned short* Op = xb;
    float* mArr = (float*)(ws + 3538944);
    float* lArr = mArr + 196608;

    convert_all<<<dim3(3072 + 576), 256, 0, stream>>>(x, wq, wk, wv, wo, xb, wqkvT, woT);
    gemm_qkv<<<dim3(SEQ / 128, 3 * EMB / 128), 256, 0, stream>>>(
        xb, wqkvT, bq, bk, bv, QKb, Vtb);
    attn_kernel<<<dim3(12 * 68), 512, 0, stream>>>(QKb, Vtb, ctxb, Op, mArr, lArr);
    merge_kernel<<<dim3(264), 256, 0, stream>>>(Op, mArr, lArr, ctxb);
    gemm_out<<<dim3(SEQ / 64, EMB / 128), 256, 0, stream>>>(ctxb, woT, bo, (float*)d_out);
}

// Round 11
// 186.449 us; speedup vs baseline: 1.2234x; 1.0447x over previous
//
#include <hip/hip_runtime.h>
#include <stdint.h>

#define SEQ 4096
#define EMB 768
#define HEADS 12
#define HD 64

typedef __attribute__((ext_vector_type(8))) short short8;
typedef __attribute__((ext_vector_type(4))) short short4v;
typedef __attribute__((ext_vector_type(8))) __bf16 bf16x8;
typedef __attribute__((ext_vector_type(4))) __bf16 bf16x4;
typedef __attribute__((ext_vector_type(4))) float f32x4;

// scale * log2(e) folded into Q: (1/sqrt(64)) * 1.4426950408889634
#define QSCALE 0.18033688011112043f

static __device__ __forceinline__ unsigned short f2bf(float f) {
    unsigned int u = __builtin_bit_cast(unsigned int, f);
    unsigned int r = 0x7fffu + ((u >> 16) & 1u);
    u += r;
    return (unsigned short)(u >> 16);
}

static __device__ __forceinline__ f32x4 mfma32(short8 a, short8 b, f32x4 c) {
    return __builtin_amdgcn_mfma_f32_16x16x32_bf16(
        __builtin_bit_cast(bf16x8, a), __builtin_bit_cast(bf16x8, b), c, 0, 0, 0);
}

static __device__ __forceinline__ f32x4 mfma16(short4v a, short4v b, f32x4 c) {
#if __has_builtin(__builtin_amdgcn_mfma_f32_16x16x16_bf16)
    return __builtin_amdgcn_mfma_f32_16x16x16_bf16(
        __builtin_bit_cast(bf16x4, a), __builtin_bit_cast(bf16x4, b), c, 0, 0, 0);
#else
    return __builtin_amdgcn_mfma_f32_16x16x16bf16_1k(a, b, c, 0, 0, 0);
#endif
}

static __device__ __forceinline__ short4v pack4bf(float a, float b, float c, float d) {
#if __has_builtin(__builtin_amdgcn_cvt_pk_bf16_f32)
    typedef __attribute__((ext_vector_type(2))) __bf16 bf16x2;
    bf16x2 lo = __builtin_amdgcn_cvt_pk_bf16_f32(a, b);
    bf16x2 hi = __builtin_amdgcn_cvt_pk_bf16_f32(c, d);
    uint2 u = {__builtin_bit_cast(unsigned int, lo), __builtin_bit_cast(unsigned int, hi)};
    return __builtin_bit_cast(short4v, u);
#else
    short4v p;
    p[0] = (short)f2bf(a); p[1] = (short)f2bf(b);
    p[2] = (short)f2bf(c); p[3] = (short)f2bf(d);
    return p;
#endif
}

static __device__ __forceinline__ void load_lds16(const void* g, void* l) {
    __builtin_amdgcn_global_load_lds(
        (const __attribute__((address_space(1))) unsigned int*)(uintptr_t)g,
        (__attribute__((address_space(3))) unsigned int*)(uintptr_t)l, 16, 0, 0);
}

// partial-id for (h, i128, ch>=1); 36 slots/head, 432 total
static __device__ __forceinline__ int pid_of(int h, int i128, int ch) {
    int b = (i128 < 20) ? (i128 - 10)
                        : (i128 < 30 ? 10 + (i128 - 20) * 2 : 30 + (i128 - 30) * 3);
    return h * 36 + b + (ch - 1);
}

// online-softmax step over one 64-k tile held as st[4] (S^T layout)
static __device__ __forceinline__ void softmax_step(f32x4* st, float& m_i, float& l_i,
                                                    f32x4* O, short4v* pk) {
    float mx = -3.0e38f;
    for (int nt = 0; nt < 4; nt++)
        for (int r = 0; r < 4; r++) mx = fmaxf(mx, st[nt][r]);
    mx = fmaxf(mx, __shfl_xor(mx, 16));
    mx = fmaxf(mx, __shfl_xor(mx, 32));
    const bool inc = mx > m_i;
    if (__ballot(inc)) {
        const float mn = inc ? mx : m_i;
        const float alpha = __builtin_amdgcn_exp2f(m_i - mn);
        m_i = mn;
        l_i *= alpha;
        for (int dt = 0; dt < 4; dt++)
            for (int r = 0; r < 4; r++) O[dt][r] *= alpha;
    }
    float rs = 0.f;
    for (int nt = 0; nt < 4; nt++) {
        float p0 = __builtin_amdgcn_exp2f(st[nt][0] - m_i);
        float p1 = __builtin_amdgcn_exp2f(st[nt][1] - m_i);
        float p2 = __builtin_amdgcn_exp2f(st[nt][2] - m_i);
        float p3 = __builtin_amdgcn_exp2f(st[nt][3] - m_i);
        rs += p0 + p1 + p2 + p3;
        pk[nt] = pack4bf(p0, p1, p2, p3);
    }
    rs += __shfl_xor(rs, 16);
    rs += __shfl_xor(rs, 32);
    l_i += rs;
}

// ---------------------------------------------------------------- fused convert
__global__ __launch_bounds__(256) void convert_all(const float* __restrict__ x,
                                                   const float* __restrict__ wq,
                                                   const float* __restrict__ wk,
                                                   const float* __restrict__ wv,
                                                   const float* __restrict__ wo,
                                                   unsigned short* __restrict__ xb,
                                                   unsigned short* __restrict__ wqkvT,
                                                   unsigned short* __restrict__ woT) {
    __shared__ float Ls[64][65];
    const int bid = blockIdx.x;
    if (bid < 3072) {
        int i = bid * 256 + threadIdx.x;
        float4 v = ((const float4*)x)[i];
        ushort4 o = {f2bf(v.x), f2bf(v.y), f2bf(v.z), f2bf(v.w)};
        ((ushort4*)xb)[i] = o;
        return;
    }
    const int idx = bid - 3072;
    const int z = idx / 144;
    const int bx = (idx % 144) / 12, by = idx % 12;
    const float* W = (z == 0) ? wq : (z == 1) ? wk : (z == 2) ? wv : wo;
    unsigned short* dst = (z < 3) ? (wqkvT + (size_t)z * EMB * EMB) : woT;
    const int k0 = bx * 64, n0 = by * 64;
    const int r = threadIdx.x >> 2, c0 = (threadIdx.x & 3) * 16;
    for (int j = 0; j < 16; j += 4) {
        float4 v = *(const float4*)&W[(size_t)(k0 + r) * EMB + n0 + c0 + j];
        Ls[r][c0 + j] = v.x;
        Ls[r][c0 + j + 1] = v.y;
        Ls[r][c0 + j + 2] = v.z;
        Ls[r][c0 + j + 3] = v.w;
    }
    __syncthreads();
    unsigned short tmp[16];
    for (int j = 0; j < 16; j++) tmp[j] = f2bf(Ls[c0 + j][r]);
    *(uint4*)&dst[(size_t)(n0 + r) * EMB + k0 + c0] = *(uint4*)tmp;
    *(uint4*)&dst[(size_t)(n0 + r) * EMB + k0 + c0 + 8] = *(uint4*)(tmp + 8);
}

// ---------------------------------------------------------------- 128x128 QKV GEMM
// Single-barrier double-buffered BK=32 staging via global_load_lds DMA (R10 —
// good for MFMA-bound GEMMs).
__global__ __launch_bounds__(256) void gemm_qkv(const unsigned short* __restrict__ A,
                                                const unsigned short* __restrict__ Bt,
                                                const float* __restrict__ b0p,
                                                const float* __restrict__ b1p,
                                                const float* __restrict__ b2p,
                                                unsigned short* __restrict__ QKb,
                                                unsigned short* __restrict__ Vtb) {
    __shared__ __align__(16) unsigned short SMEM[16384];  // [buf*8192]: As 4096 | Bs 4096
    const int tid = threadIdx.x;
    const int wave = tid >> 6, lane = tid & 63, quad = lane >> 4, l16 = lane & 15;
    const int m0 = blockIdx.x * 128, n0 = blockIdx.y * 128;
    const int wm = (wave >> 1) * 64, wn = (wave & 1) * 64;
    const int lrow = lane >> 2, lcol = (lane & 3) * 8;

    f32x4 acc[4][4] = {};

    for (int t = 0; t < 2; t++) {
        int row = wave * 32 + t * 16 + lrow;
        load_lds16(&A[(size_t)(m0 + row) * EMB + lcol], &SMEM[(wave * 2 + t) * 512]);
        load_lds16(&Bt[(size_t)(n0 + row) * EMB + lcol], &SMEM[4096 + (wave * 2 + t) * 512]);
    }
    int buf = 0;
    for (int k0 = 0; k0 < EMB; k0 += 32) {
        __syncthreads();  // drains this buf's DMA; other buf free
        if (k0 + 32 < EMB) {
            unsigned short* A_ = &SMEM[(buf ^ 1) * 8192];
            unsigned short* B_ = A_ + 4096;
            for (int t = 0; t < 2; t++) {
                int row = wave * 32 + t * 16 + lrow;
                load_lds16(&A[(size_t)(m0 + row) * EMB + k0 + 32 + lcol], &A_[(wave * 2 + t) * 512]);
                load_lds16(&Bt[(size_t)(n0 + row) * EMB + k0 + 32 + lcol], &B_[(wave * 2 + t) * 512]);
            }
        }
        const unsigned short* A_ = &SMEM[buf * 8192];
        const unsigned short* B_ = A_ + 4096;
        short8 a[4], b[4];
        for (int i = 0; i < 4; i++) a[i] = *(const short8*)&A_[(wm + i * 16 + l16) * 32 + quad * 8];
        for (int i = 0; i < 4; i++) b[i] = *(const short8*)&B_[(wn + i * 16 + l16) * 32 + quad * 8];
        for (int i = 0; i < 4; i++)
            for (int j = 0; j < 4; j++) acc[i][j] = mfma32(a[i], b[j], acc[i][j]);
        buf ^= 1;
    }

    const int z = n0 / EMB;  // block-uniform: 0=Q, 1=K, 2=V
    if (z < 2) {
        const float* bias = z ? b1p : b0p;
        const float sc = z ? 1.0f : QSCALE;
        for (int i = 0; i < 4; i++)
            for (int j = 0; j < 4; j++) {
                int mbase = m0 + wm + i * 16 + quad * 4;
                int n = n0 + wn + j * 16 + l16;  // 0..1535 natural col
                float bv = bias[n - z * EMB];
                for (int r = 0; r < 4; r++)
                    QKb[(size_t)(mbase + r) * 1536 + n] = f2bf((acc[i][j][r] + bv) * sc);
            }
    } else {
        const int nn = n0 + wn + l16 - 2 * EMB;
        for (int j = 0; j < 4; j++) {
            __syncthreads();
            const float bv = b2p[nn + j * 16];
            const int nloc = (wave & 1) * 16 + l16;
            for (int i = 0; i < 4; i++) {
                ushort4 pk;
                pk.x = f2bf(acc[i][j][0] + bv);
                pk.y = f2bf(acc[i][j][1] + bv);
                pk.z = f2bf(acc[i][j][2] + bv);
                pk.w = f2bf(acc[i][j][3] + bv);
                *(ushort4*)&SMEM[nloc * 136 + wm + i * 16 + quad * 4] = pk;
            }
            __syncthreads();
            const int nl = tid >> 3, c = tid & 7;
            const int ng = (nl >> 4) * 64 + j * 16 + (nl & 15) + n0 - 2 * EMB;
            const int hh = ng >> 6, dd = ng & 63;
            unsigned short* dst = &Vtb[(size_t)(hh * HD + dd) * SEQ + m0];
            *(uint4*)&dst[c * 8] = *(uint4*)&SMEM[nl * 136 + c * 8];
            *(uint4*)&dst[64 + c * 8] = *(uint4*)&SMEM[nl * 136 + 64 + c * 8];
        }
    }
}

// ---------------------------------------------------------------- 64x128 out-proj GEMM
__global__ __launch_bounds__(256) void gemm_out(const unsigned short* __restrict__ A,
                                                const unsigned short* __restrict__ Bt,
                                                const float* __restrict__ bias,
                                                float* __restrict__ outp) {
    __shared__ __align__(16) unsigned short SMEM[12288];  // As[2]@0/2048, Bs[2]@4096/8192
    const int tid = threadIdx.x;
    const int wave = tid >> 6, lane = tid & 63, quad = lane >> 4, l16 = lane & 15;
    const int m0 = blockIdx.x * 64, n0 = blockIdx.y * 128;
    const int wm = (wave >> 1) * 32, wn = (wave & 1) * 64;
    const int lrow = lane >> 2, lcol = (lane & 3) * 8;

    f32x4 acc[2][4] = {};

    load_lds16(&A[(size_t)(m0 + wave * 16 + lrow) * EMB + lcol], &SMEM[wave * 512]);
    for (int t = 0; t < 2; t++) {
        int row = wave * 32 + t * 16 + lrow;
        load_lds16(&Bt[(size_t)(n0 + row) * EMB + lcol], &SMEM[4096 + (wave * 2 + t) * 512]);
    }
    int buf = 0;
    for (int k0 = 0; k0 < EMB; k0 += 32) {
        __syncthreads();
        if (k0 + 32 < EMB) {
            unsigned short* A_ = &SMEM[(buf ^ 1) * 2048];
            unsigned short* B_ = &SMEM[4096 + (buf ^ 1) * 4096];
            load_lds16(&A[(size_t)(m0 + wave * 16 + lrow) * EMB + k0 + 32 + lcol], &A_[wave * 512]);
            for (int t = 0; t < 2; t++) {
                int row = wave * 32 + t * 16 + lrow;
                load_lds16(&Bt[(size_t)(n0 + row) * EMB + k0 + 32 + lcol], &B_[(wave * 2 + t) * 512]);
            }
        }
        const unsigned short* A_ = &SMEM[buf * 2048];
        const unsigned short* B_ = &SMEM[4096 + buf * 4096];
        short8 a[2], b[4];
        for (int i = 0; i < 2; i++) a[i] = *(const short8*)&A_[(wm + i * 16 + l16) * 32 + quad * 8];
        for (int j = 0; j < 4; j++) b[j] = *(const short8*)&B_[(wn + j * 16 + l16) * 32 + quad * 8];
        for (int i = 0; i < 2; i++)
            for (int j = 0; j < 4; j++) acc[i][j] = mfma32(a[i], b[j], acc[i][j]);
        buf ^= 1;
    }

    for (int i = 0; i < 2; i++)
        for (int j = 0; j < 4; j++) {
            int mbase = m0 + wm + i * 16 + quad * 4;
            int n = n0 + wn + j * 16 + l16;
            float bv = bias[n];
            for (int r = 0; r < 4; r++) outp[(size_t)(mbase + r) * EMB + n] = acc[i][j][r] + bv;
        }
}

// ---------------------------------------------------------------- attention
// R8 verbatim: 816 blocks = 12 heads x 68 chunks; 512 threads = 8 waves over a
// 128-q tile; 16 q-rows/wave; register-prefetch staging + XOR store swizzle
// (0 measured conflicts); 2 barriers/iter; ~48 VGPR -> 32 waves/CU.
// R7 (2q/wave + reg cap) spilled; R9 (2q/wave, no cap) halved occupancy;
// R10 (DMA staging) contended on the LDS port. This shape is the optimum.
__global__ __launch_bounds__(512) void attn_kernel(const unsigned short* __restrict__ QKb,
                                                   const unsigned short* __restrict__ Vtb,
                                                   unsigned short* __restrict__ ctxb,
                                                   unsigned short* __restrict__ Op,
                                                   float* __restrict__ mArr,
                                                   float* __restrict__ lArr) {
    __shared__ __align__(16) unsigned short Ks[64 * 64];
    __shared__ __align__(16) unsigned short Vs[64 * 64];

    const int bid = blockIdx.x;
    const int h = bid % HEADS;
    const int r2 = 67 - bid / HEADS;  // big i128 (long chunks) first
    int i128, ch, nch;
    if (r2 < 10) {
        i128 = r2; ch = 0; nch = 1;
    } else if (r2 < 30) {
        int t = r2 - 10; i128 = 10 + (t >> 1); ch = t & 1; nch = 2;
    } else if (r2 < 60) {
        int t = r2 - 30; i128 = 20 + t / 3; ch = t % 3; nch = 3;
    } else {
        int t = r2 - 60; i128 = 30 + (t >> 2); ch = t & 3; nch = 4;
    }
    const int T = 2 * i128 + 2;
    const int kb = ch * T / nch;
    const int ke = (ch + 1) * T / nch - 1;
    const int qbase = i128 * 128;
    const int tid = threadIdx.x;
    const int wave = tid >> 6, lane = tid & 63, quad = lane >> 4, l16 = lane & 15;

    const unsigned short* Qg = QKb + (size_t)h * HD;          // row stride 1536
    const unsigned short* Kg = QKb + (size_t)(EMB + h * HD);  // row stride 1536
    const unsigned short* Vh = Vtb + (size_t)h * HD * SEQ;    // [d][m]

    const int q = qbase + wave * 16 + l16;  // waves 0..7 cover 128 q-rows
    const short8 bQ0 = *(const short8*)&Qg[(size_t)q * 1536 + quad * 8];
    const short8 bQ1 = *(const short8*)&Qg[(size_t)q * 1536 + 32 + quad * 8];

    const int row = tid >> 3, t8 = tid & 7;  // 512 threads: 64 rows x 8 chunks
    const int swk = row & 7, swv = row & 15;

    f32x4 O[4] = {};
    float m_i = -3.0e38f, l_i = 0.f;

    uint4 kr, vr;
    {
        const int kb64 = kb * 64;
        kr = *(const uint4*)&Kg[(size_t)(kb64 + row) * 1536 + t8 * 8];
        vr = *(const uint4*)&Vh[(size_t)row * SEQ + kb64 + t8 * 8];
    }

    for (int kt = kb; kt <= ke; kt++) {
        const int kbase = kt * 64;
        __syncthreads();
        *(uint4*)&Ks[row * 64 + (t8 ^ swk) * 8] = kr;
        *(uint2*)&Vs[row * 64 + ((2 * t8) ^ swv) * 4] = ((const uint2*)&vr)[0];
        *(uint2*)&Vs[row * 64 + ((2 * t8 + 1) ^ swv) * 4] = ((const uint2*)&vr)[1];
        if (kt < ke) {
            const int nb = kbase + 64;
            kr = *(const uint4*)&Kg[(size_t)(nb + row) * 1536 + t8 * 8];
            vr = *(const uint4*)&Vh[(size_t)row * SEQ + nb + t8 * 8];
        }
        __syncthreads();

        // wave-uniform: is this tile entirely above this wave's causal row?
        if (kbase > qbase + wave * 16 + 15) continue;

        // S^T tiles: lane holds q=l16 (col), k=kbase+nt*16+quad*4+r (row)
        const int swr = l16 & 7;
        f32x4 st[4];
        for (int nt = 0; nt < 4; nt++) {
            short8 aK0 = *(const short8*)&Ks[(nt * 16 + l16) * 64 + (quad ^ swr) * 8];
            short8 aK1 = *(const short8*)&Ks[(nt * 16 + l16) * 64 + ((quad + 4) ^ swr) * 8];
            f32x4 z = {};
            z = mfma32(aK0, bQ0, z);
            z = mfma32(aK1, bQ1, z);
            st[nt] = z;
        }
        if (kbase + 63 > qbase + wave * 16) {  // diagonal tile for this wave
            for (int nt = 0; nt < 4; nt++)
                for (int r = 0; r < 4; r++)
                    if (kbase + nt * 16 + quad * 4 + r > q) st[nt][r] = -INFINITY;
        }

        short4v pk[4];
        softmax_step(st, m_i, l_i, O, pk);

        // O^T += V^T P^T : A = Vs rows (d=l16), B = pk (in-register)
        for (int dt = 0; dt < 4; dt++)
            for (int nt = 0; nt < 4; nt++) {
                short4v av =
                    *(const short4v*)&Vs[(dt * 16 + l16) * 64 + ((4 * nt + quad) ^ l16) * 4];
                O[dt] = mfma16(av, pk[nt], O[dt]);
            }
    }

    const int ql = wave * 16 + l16;  // 0..127
    if (nch == 1) {
        const float inv = 1.f / l_i;
        for (int dt = 0; dt < 4; dt++) {
            ushort4 o;
            o.x = f2bf(O[dt][0] * inv);
            o.y = f2bf(O[dt][1] * inv);
            o.z = f2bf(O[dt][2] * inv);
            o.w = f2bf(O[dt][3] * inv);
            *(ushort4*)&ctxb[(size_t)q * EMB + h * HD + dt * 16 + quad * 4] = o;
        }
    } else {
        if (ch == 0) {
            for (int dt = 0; dt < 4; dt++) {
                ushort4 o;
                o.x = f2bf(O[dt][0]);
                o.y = f2bf(O[dt][1]);
                o.z = f2bf(O[dt][2]);
                o.w = f2bf(O[dt][3]);
                *(ushort4*)&ctxb[(size_t)q * EMB + h * HD + dt * 16 + quad * 4] = o;
            }
        } else {
            const int pid = pid_of(h, i128, ch);
            for (int dt = 0; dt < 4; dt++) {
                ushort4 o;
                o.x = f2bf(O[dt][0]);
                o.y = f2bf(O[dt][1]);
                o.z = f2bf(O[dt][2]);
                o.w = f2bf(O[dt][3]);
                *(ushort4*)&Op[(size_t)pid * 8192 + ql * 64 + dt * 16 + quad * 4] = o;
            }
        }
        if (quad == 0) {
            const int mli = ((h * 32 + i128) * 4 + ch) * 128 + ql;
            mArr[mli] = m_i;
            lArr[mli] = l_i;
        }
    }
}

// ---------------------------------------------------------------- merge (i128>=10)
__global__ __launch_bounds__(256) void merge_kernel(const unsigned short* __restrict__ Op,
                                                    const float* __restrict__ mArr,
                                                    const float* __restrict__ lArr,
                                                    unsigned short* __restrict__ ctxb) {
    const int gid = blockIdx.x;  // 0..263
    const int h = gid % HEADS;
    const int i128 = 10 + gid / HEADS;
    const int nch = (i128 < 20) ? 2 : (i128 < 30) ? 3 : 4;
    const int q = threadIdx.x >> 1, d0 = (threadIdx.x & 1) * 32;
    const int mlbase = (h * 32 + i128) * 4;

    float mc[4], lc[4];
    for (int c = 0; c < nch; c++) {
        mc[c] = mArr[(mlbase + c) * 128 + q];
        lc[c] = lArr[(mlbase + c) * 128 + q];
    }
    float M = mc[0];
    for (int c = 1; c < nch; c++) M = fmaxf(M, mc[c]);
    float w[4], L = 0.f;
    for (int c = 0; c < nch; c++) {
        w[c] = __builtin_amdgcn_exp2f(mc[c] - M);
        L += w[c] * lc[c];
    }
    const float inv = 1.f / L;
    for (int c = 0; c < nch; c++) w[c] *= inv;

    unsigned short* dst = &ctxb[(size_t)(i128 * 128 + q) * EMB + h * HD + d0];
    for (int jj = 0; jj < 32; jj += 8) {
        uint4 u0 = *(const uint4*)&dst[jj];  // chunk0 (unnormalized) in place
        float f[8];
        const unsigned short* p0 = (const unsigned short*)&u0;
        for (int t = 0; t < 8; t++)
            f[t] = w[0] * __builtin_bit_cast(float, (unsigned int)p0[t] << 16);
        for (int c = 1; c < nch; c++) {
            const int pid = pid_of(h, i128, c);
            uint4 u = *(const uint4*)&Op[(size_t)pid * 8192 + q * 64 + d0 + jj];
            const unsigned short* p = (const unsigned short*)&u;
            for (int t = 0; t < 8; t++)
                f[t] += w[c] * __builtin_bit_cast(float, (unsigned int)p[t] << 16);
        }
        unsigned short o[8];
        for (int t = 0; t < 8; t++) o[t] = f2bf(f[t]);
        *(uint4*)&dst[jj] = *(uint4*)o;
    }
}

// ---------------------------------------------------------------- launch
extern "C" void kernel_launch(void* const* d_in, const int* in_sizes, int n_in,
                              void* d_out, int out_size, void* d_ws, size_t ws_size,
                              hipStream_t stream) {
    const float* x = (const float*)d_in[0];
    const float* wq = (const float*)d_in[1];
    const float* bq = (const float*)d_in[2];
    const float* wk = (const float*)d_in[3];
    const float* bk = (const float*)d_in[4];
    const float* wv = (const float*)d_in[5];
    const float* bv = (const float*)d_in[6];
    const float* wo = (const float*)d_in[7];
    const float* bo = (const float*)d_in[8];

    unsigned short* ws = (unsigned short*)d_ws;
    unsigned short* xb = ws;                          // 3,145,728 ush
    unsigned short* wqkvT = xb + SEQ * EMB;           // 1,769,472
    unsigned short* woT = wqkvT + 3 * EMB * EMB;      // 589,824
    unsigned short* QKb = woT + EMB * EMB;            // 4096*1536
    unsigned short* Vtb = QKb + (size_t)SEQ * 1536;   // 3,145,728
    unsigned short* ctxb = Vtb + HEADS * SEQ * HD;    // 3,145,728
    // attn-phase scratch aliases xb+wqkvT (dead after gemm_qkv):
    // Op 432*8192 = 3,538,944 ush; mArr/lArr 196,608 f32 each -> ends 4,325,376
    unsigned short* Op = xb;
    float* mArr = (float*)(ws + 3538944);
    float* lArr = mArr + 196608;

    convert_all<<<dim3(3072 + 576), 256, 0, stream>>>(x, wq, wk, wv, wo, xb, wqkvT, woT);
    gemm_qkv<<<dim3(SEQ / 128, 3 * EMB / 128), 256, 0, stream>>>(
        xb, wqkvT, bq, bk, bv, QKb, Vtb);
    attn_kernel<<<dim3(12 * 68), 512, 0, stream>>>(QKb, Vtb, ctxb, Op, mArr, lArr);
    merge_kernel<<<dim3(264), 256, 0, stream>>>(Op, mArr, lArr, ctxb);
    gemm_out<<<dim3(SEQ / 64, EMB / 128), 256, 0, stream>>>(ctxb, woT, bo, (float*)d_out);
}